// Round 1
// baseline (118.856 us; speedup 1.0000x reference)
//
#include <hip/hip_runtime.h>
#include <hip/hip_bf16.h>

// ---------------------------------------------------------------------------
// Compile-time Clifford algebra tables (N_GEN=6, DIM=64), replicating the
// reference _build_algebra() exactly: blades sorted by (popcount, value).
// ---------------------------------------------------------------------------
namespace alg {
constexpr int pc(int v) { int c = 0; while (v) { c += v & 1; v >>= 1; } return c; }
constexpr int swap_sign_i(int a, int b) {
  int s = 0; a >>= 1;
  while (a) { s += pc(a & b); a >>= 1; }
  return (s & 1) ? -1 : 1;
}
struct Tables {
  int blade[64]; int index[64]; int cls[64];
  int itab[64][64]; int sgn[64][64]; int ct[64][64];
  constexpr Tables() : blade{}, index{}, cls{}, itab{}, sgn{}, ct{} {
    int pos = 0;
    for (int g = 0; g <= 6; ++g)
      for (int b = 0; b < 64; ++b)
        if (pc(b) == g) { blade[pos] = b; index[b] = pos; ++pos; }
    for (int i = 0; i < 64; ++i) cls[i] = pc(blade[i]) & 3;
    for (int J = 0; J < 64; ++J)
      for (int K = 0; K < 64; ++K) {
        int bj = blade[J], bk = blade[K], bi = bj ^ bk;
        int I = index[bi];
        itab[J][K] = I;
        sgn[J][K] = swap_sign_i(bi, bk);
        ct[J][K] = cls[I] * 16 + cls[J] * 4 + cls[K];
      }
  }
};
constexpr Tables T{};
}  // namespace alg

__device__ __forceinline__ float rfl(float v) {
  return __uint_as_float(__builtin_amdgcn_readfirstlane(__float_as_uint(v)));
}

// ---------------------------------------------------------------------------
// Kernel 1 (prep): blocks 0..511  : transpose x[b][m][i] -> xT[i][m][b]
//                  blocks 512..767: Wt[c][m][n] = w_lin[n][m][c]
//                  blocks 768..799: g[n][ci*16+cj*4+ck] from w_gp/path_idx
// ---------------------------------------------------------------------------
__global__ __launch_bounds__(256) void kprep(
    const float* __restrict__ x, const float* __restrict__ wlin,
    const float* __restrict__ wgp, const int* __restrict__ pidx, int P,
    float* __restrict__ xT, float* __restrict__ Wt, float* __restrict__ g) {
  int bid = blockIdx.x;
  if (bid < 512) {
    __shared__ float tile[64 * 65];
    int m = bid >> 2, bc = (bid & 3) << 6;
    int lane = threadIdx.x & 63, row = threadIdx.x >> 6;
#pragma unroll
    for (int p = 0; p < 16; ++p) {
      int b = p * 4 + row;
      tile[lane * 65 + b] = x[(bc + b) * 8192 + m * 64 + lane];
    }
    __syncthreads();
#pragma unroll
    for (int p = 0; p < 16; ++p) {
      int il = p * 4 + row;
      xT[il * 32768 + m * 256 + bc + lane] = tile[il * 65 + lane];
    }
  } else if (bid < 768) {
    int id = (bid - 512) * 256 + threadIdx.x;  // 0..65535
    int n = id & 127, m = (id >> 7) & 127, c = id >> 14;
    Wt[c * 16384 + m * 128 + n] = wlin[n * 512 + m * 4 + c];
  } else {
    int id = (bid - 768) * 256 + threadIdx.x;  // 0..8191
    int n = id >> 6, t = id & 63;
    int ti = t >> 4, tj = (t >> 2) & 3, tk = t & 3;
    float v = 0.f;
    for (int p = 0; p < P; ++p)
      if (pidx[p * 3] == ti && pidx[p * 3 + 1] == tj && pidx[p * 3 + 2] == tk)
        v = wgp[n * P + p];
    g[n * 64 + t] = v;
  }
}

// ---------------------------------------------------------------------------
// Kernel 2 (linear): xr[b,n,i] = sum_m x[b,m,i]*Wt[cls_i][m][n]  (+b_lin at i=0)
// Wave layout: lane = b, wave handles (blade i, n-tile of 32, b-chunk of 64).
// Weights are wave-uniform -> scalar loads; inner loop = 32 v_fmac per m.
// Output layout xrT[n][i][b] (coalesced, lane = b).
// ---------------------------------------------------------------------------
__global__ __launch_bounds__(256) void klin(
    const float* __restrict__ xT, const float* __restrict__ Wt,
    const float* __restrict__ blin, float* __restrict__ xrT) {
  int wid = __builtin_amdgcn_readfirstlane(blockIdx.x * 4 + (threadIdx.x >> 6));
  int lane = threadIdx.x & 63;
  int i = wid & 63;
  int nt = (wid >> 6) & 3;
  int bc = (wid >> 8) << 6;
  int ci = alg::T.cls[i];

  const float* xp = xT + i * 32768 + bc + lane;
  const float* wp = Wt + ci * 16384 + nt * 32;
  float acc[32];
#pragma unroll
  for (int t = 0; t < 32; ++t) acc[t] = 0.f;

#pragma unroll 4
  for (int m = 0; m < 128; ++m) {
    float xv = xp[m * 256];
#pragma unroll
    for (int t = 0; t < 32; ++t) acc[t] = fmaf(xv, wp[m * 128 + t], acc[t]);
  }
  if (i == 0) {
#pragma unroll
    for (int t = 0; t < 32; ++t) acc[t] += blin[nt * 32 + t];
  }
#pragma unroll
  for (int t = 0; t < 32; ++t)
    xrT[(nt * 32 + t) * 16384 + i * 256 + bc + lane] = acc[t];
}

// ---------------------------------------------------------------------------
// Kernel 3 (product): fused gating + geometric product.
// Wave layout: lane = b. One wave (=one 64-thread block) handles
// (n, b-chunk of 64, j-range of 16). All algebra indices compile-time.
// Inner loop: 64k x 16j fully unrolled -> pure v_mul + v_fmac stream.
// ---------------------------------------------------------------------------
template <int JW>
__device__ __forceinline__ void prod_body(
    const float* __restrict__ xT, const float* __restrict__ xr,
    const float* __restrict__ g, const float* __restrict__ an,
    float* __restrict__ out, int n, int bc, int lane) {
  float xv[64], rv[64];
#pragma unroll
  for (int i = 0; i < 64; ++i) xv[i] = xT[i * 32768 + n * 256 + bc + lane];
#pragma unroll
  for (int i = 0; i < 64; ++i) rv[i] = xr[n * 16384 + i * 256 + bc + lane];

  // g[n][0..63] -> wave-uniform scalars (SGPRs)
  float gl[64];
#pragma unroll
  for (int t = 0; t < 64; ++t) gl[t] = rfl(g[n * 64 + t]);

  // ---- gating (per lane = per b) ----
  float s[4] = {0.f, 0.f, 0.f, 0.f};
#pragma unroll
  for (int i = 0; i < 64; ++i) {
    const int c = alg::T.cls[i];
    s[c] = fmaf(rv[i], rv[i], s[c]);
  }
  float r[4];
#pragma unroll
  for (int c = 0; c < 4; ++c) {
    float a = an[n * 4 + c];
    float sig = 1.f / (1.f + __expf(-a));
    float gate = sig * (sqrtf(s[c]) - 1.f) + 1.f;
    r[c] = 1.f / (gate + 1e-6f);
  }
#pragma unroll
  for (int i = 0; i < 64; ++i) rv[i] *= r[alg::T.cls[i]];

  // ---- product ----
  float acc[16];
#pragma unroll
  for (int jj = 0; jj < 16; ++jj) acc[jj] = 0.f;
#pragma unroll
  for (int k = 0; k < 64; ++k) {
#pragma unroll
    for (int jj = 0; jj < 16; ++jj) {
      const int j = JW * 16 + jj;
      const int ii = alg::T.itab[j][k];
      const int tt = alg::T.ct[j][k];
      float t = xv[ii] * rv[k];
      acc[jj] = fmaf(alg::T.sgn[j][k] > 0 ? gl[tt] : -gl[tt], t, acc[jj]);
    }
  }

  // ---- transpose 16x64 tile through LDS, coalesced store ----
  __shared__ float ot[16 * 68];
#pragma unroll
  for (int jj = 0; jj < 16; ++jj) ot[jj * 68 + lane] = acc[jj];
  __syncthreads();
#pragma unroll
  for (int p = 0; p < 16; ++p) {
    int j = lane & 15, br = p * 4 + (lane >> 4);
    out[(bc + br) * 8192 + n * 64 + JW * 16 + j] = ot[j * 68 + br];
  }
}

__global__ __launch_bounds__(64) void kprod(
    const float* __restrict__ xT, const float* __restrict__ xr,
    const float* __restrict__ g, const float* __restrict__ an,
    float* __restrict__ out) {
  int bid = blockIdx.x;
  int jw = bid >> 9;
  int rest = bid & 511;
  int n = rest >> 2;
  int bc = (rest & 3) << 6;
  int lane = threadIdx.x;
  switch (jw) {
    case 0: prod_body<0>(xT, xr, g, an, out, n, bc, lane); break;
    case 1: prod_body<1>(xT, xr, g, an, out, n, bc, lane); break;
    case 2: prod_body<2>(xT, xr, g, an, out, n, bc, lane); break;
    case 3: prod_body<3>(xT, xr, g, an, out, n, bc, lane); break;
  }
}

// ---------------------------------------------------------------------------
extern "C" void kernel_launch(void* const* d_in, const int* in_sizes, int n_in,
                              void* d_out, int out_size, void* d_ws, size_t ws_size,
                              hipStream_t stream) {
  (void)n_in; (void)out_size; (void)ws_size;
  const float* x    = (const float*)d_in[0];
  const float* wgp  = (const float*)d_in[1];
  const float* wlin = (const float*)d_in[2];
  const float* blin = (const float*)d_in[3];
  const float* an   = (const float*)d_in[4];
  const int*   pidx = (const int*)d_in[7];
  int P = in_sizes[7] / 3;

  float* ws  = (float*)d_ws;
  float* xT  = ws;                // 2,097,152 floats (8 MB)
  float* xrT = ws + 2097152;      // 2,097,152 floats (8 MB)
  float* Wt  = ws + 4194304;      // 65,536 floats (256 KB)
  float* g   = ws + 4259840;      // 8,192 floats (32 KB)

  kprep<<<800, 256, 0, stream>>>(x, wlin, wgp, pidx, P, xT, Wt, g);
  klin<<<256, 256, 0, stream>>>(xT, Wt, blin, xrT);
  kprod<<<2048, 64, 0, stream>>>(xT, xrT, g, an, (float*)d_out);
}

// Round 2
// 111.657 us; speedup vs baseline: 1.0645x; 1.0645x over previous
//
#include <hip/hip_runtime.h>
#include <hip/hip_bf16.h>

// ---------------------------------------------------------------------------
// Compile-time Clifford algebra tables (N_GEN=6, DIM=64), replicating the
// reference _build_algebra() exactly: blades sorted by (popcount, value).
// ---------------------------------------------------------------------------
namespace alg {
constexpr int pc(int v) { int c = 0; while (v) { c += v & 1; v >>= 1; } return c; }
constexpr int swap_sign_i(int a, int b) {
  int s = 0; a >>= 1;
  while (a) { s += pc(a & b); a >>= 1; }
  return (s & 1) ? -1 : 1;
}
struct Tables {
  int blade[64]; int index[64]; int cls[64];
  int itab[64][64]; int sgn[64][64]; int ct[64][64];
  constexpr Tables() : blade{}, index{}, cls{}, itab{}, sgn{}, ct{} {
    int pos = 0;
    for (int g = 0; g <= 6; ++g)
      for (int b = 0; b < 64; ++b)
        if (pc(b) == g) { blade[pos] = b; index[b] = pos; ++pos; }
    for (int i = 0; i < 64; ++i) cls[i] = pc(blade[i]) & 3;
    for (int J = 0; J < 64; ++J)
      for (int K = 0; K < 64; ++K) {
        int bj = blade[J], bk = blade[K], bi = bj ^ bk;
        int I = index[bi];
        itab[J][K] = I;
        sgn[J][K] = swap_sign_i(bi, bk);
        ct[J][K] = cls[I] * 16 + cls[J] * 4 + cls[K];
      }
  }
};
constexpr Tables T{};
}  // namespace alg

__device__ __forceinline__ float rfl(float v) {
  return __uint_as_float(__builtin_amdgcn_readfirstlane(__float_as_uint(v)));
}

// ---------------------------------------------------------------------------
// Kernel 1 (prep): blocks 0..511  : transpose x[b][m][i] -> xT[i][m][b]
//                  blocks 512..767: Wt[c][m][n] = w_lin[n][m][c]
//                  blocks 768..799: g[n][ci*16+cj*4+ck] from w_gp/path_idx
// ---------------------------------------------------------------------------
__global__ __launch_bounds__(256) void kprep(
    const float* __restrict__ x, const float* __restrict__ wlin,
    const float* __restrict__ wgp, const int* __restrict__ pidx, int P,
    float* __restrict__ xT, float* __restrict__ Wt, float* __restrict__ g) {
  int bid = blockIdx.x;
  if (bid < 512) {
    __shared__ float tile[64 * 65];
    int m = bid >> 2, bc = (bid & 3) << 6;
    int lane = threadIdx.x & 63, row = threadIdx.x >> 6;
#pragma unroll
    for (int p = 0; p < 16; ++p) {
      int b = p * 4 + row;
      tile[lane * 65 + b] = x[(bc + b) * 8192 + m * 64 + lane];
    }
    __syncthreads();
#pragma unroll
    for (int p = 0; p < 16; ++p) {
      int il = p * 4 + row;
      xT[il * 32768 + m * 256 + bc + lane] = tile[il * 65 + lane];
    }
  } else if (bid < 768) {
    int id = (bid - 512) * 256 + threadIdx.x;  // 0..65535
    int n = id & 127, m = (id >> 7) & 127, c = id >> 14;
    Wt[c * 16384 + m * 128 + n] = wlin[n * 512 + m * 4 + c];
  } else {
    int id = (bid - 768) * 256 + threadIdx.x;  // 0..8191
    int n = id >> 6, t = id & 63;
    int ti = t >> 4, tj = (t >> 2) & 3, tk = t & 3;
    float v = 0.f;
    for (int p = 0; p < P; ++p)
      if (pidx[p * 3] == ti && pidx[p * 3 + 1] == tj && pidx[p * 3 + 2] == tk)
        v = wgp[n * P + p];
    g[n * 64 + t] = v;
  }
}

// ---------------------------------------------------------------------------
// Kernel 2 (linear): xr[b,n,i] = sum_m x[b,m,i]*Wt[cls_i][m][n]  (+b_lin at i=0)
// Wave layout: lane = b. Wave = (blade i, n-tile of 16, b-chunk of 64).
// 2048 waves = 2 waves/SIMD (was 1). acc[16] keeps VGPRs light.
// ---------------------------------------------------------------------------
__global__ __launch_bounds__(256, 4) void klin(
    const float* __restrict__ xT, const float* __restrict__ Wt,
    const float* __restrict__ blin, float* __restrict__ xrT) {
  int wid = __builtin_amdgcn_readfirstlane(blockIdx.x * 4 + (threadIdx.x >> 6));
  int lane = threadIdx.x & 63;
  int i = wid & 63;
  int nt = (wid >> 6) & 7;   // 8 tiles of 16 n
  int bc = (wid >> 9) << 6;  // 4 chunks of 64 b
  int ci = alg::T.cls[i];

  const float* xp = xT + i * 32768 + bc + lane;
  const float* wp = Wt + ci * 16384 + nt * 16;
  float acc[16];
#pragma unroll
  for (int t = 0; t < 16; ++t) acc[t] = 0.f;

#pragma unroll 4
  for (int m = 0; m < 128; ++m) {
    float xv = xp[m * 256];
#pragma unroll
    for (int t = 0; t < 16; ++t) acc[t] = fmaf(xv, wp[m * 128 + t], acc[t]);
  }
  if (i == 0) {
#pragma unroll
    for (int t = 0; t < 16; ++t) acc[t] += blin[nt * 16 + t];
  }
#pragma unroll
  for (int t = 0; t < 16; ++t)
    xrT[(nt * 16 + t) * 16384 + i * 256 + bc + lane] = acc[t];
}

// ---------------------------------------------------------------------------
// Kernel 3 (product): fused gating + geometric product.
// Block = 256 threads = 4 waves, all sharing (n, bc); wave w computes the
// j-range [16w, 16w+16). The 4 waves' identical xv/rv loads hit L1.
// launch_bounds(256,2) -> 256-VGPR cap: xv[64]+rv[64]+acc[16]+temps fits,
// NO scratch spills (round-1's 64-thread blocks likely spilled).
// ---------------------------------------------------------------------------
template <int JW>
__device__ __forceinline__ void prod_body(
    const float* __restrict__ xT, const float* __restrict__ xr,
    const float* __restrict__ g, const float* __restrict__ an,
    float* __restrict__ out, float* __restrict__ ot, int n, int bc, int lane) {
  float xv[64], rv[64];
#pragma unroll
  for (int i = 0; i < 64; ++i) xv[i] = xT[i * 32768 + n * 256 + bc + lane];
#pragma unroll
  for (int i = 0; i < 64; ++i) rv[i] = xr[n * 16384 + i * 256 + bc + lane];

  // g[n][0..63] -> wave-uniform scalars
  float gl[64];
#pragma unroll
  for (int t = 0; t < 64; ++t) gl[t] = rfl(g[n * 64 + t]);

  // ---- gating (per lane = per b) ----
  float s[4] = {0.f, 0.f, 0.f, 0.f};
#pragma unroll
  for (int i = 0; i < 64; ++i) {
    const int c = alg::T.cls[i];
    s[c] = fmaf(rv[i], rv[i], s[c]);
  }
  float r[4];
#pragma unroll
  for (int c = 0; c < 4; ++c) {
    float a = rfl(an[n * 4 + c]);
    float sig = 1.f / (1.f + __expf(-a));
    float gate = sig * (sqrtf(s[c]) - 1.f) + 1.f;
    r[c] = 1.f / (gate + 1e-6f);
  }
#pragma unroll
  for (int i = 0; i < 64; ++i) rv[i] *= r[alg::T.cls[i]];

  // ---- product: fully unrolled, all indices compile-time ----
  float acc[16];
#pragma unroll
  for (int jj = 0; jj < 16; ++jj) acc[jj] = 0.f;
#pragma unroll
  for (int k = 0; k < 64; ++k) {
#pragma unroll
    for (int jj = 0; jj < 16; ++jj) {
      const int j = JW * 16 + jj;
      const int ii = alg::T.itab[j][k];
      const int tt = alg::T.ct[j][k];
      float t = xv[ii] * rv[k];
      acc[jj] = fmaf(alg::T.sgn[j][k] > 0 ? gl[tt] : -gl[tt], t, acc[jj]);
    }
  }

  // ---- transpose 16x64 tile through this wave's private LDS region ----
  // (wave-private region: no __syncthreads needed, only lgkmcnt which the
  //  compiler inserts)
#pragma unroll
  for (int jj = 0; jj < 16; ++jj) ot[jj * 68 + lane] = acc[jj];
  __builtin_amdgcn_s_waitcnt(0);  // lgkmcnt(0): wave-synchronous LDS round-trip
#pragma unroll
  for (int p = 0; p < 16; ++p) {
    int j = lane & 15, br = p * 4 + (lane >> 4);
    out[(bc + br) * 8192 + n * 64 + JW * 16 + j] = ot[j * 68 + br];
  }
}

__global__ __launch_bounds__(256, 2) void kprod(
    const float* __restrict__ xT, const float* __restrict__ xr,
    const float* __restrict__ g, const float* __restrict__ an,
    float* __restrict__ out) {
  __shared__ float ot[4][16 * 68];
  int bid = blockIdx.x;       // 512 blocks: (n in 0..127) x (bc in 0..3)
  int n = bid >> 2;
  int bc = (bid & 3) << 6;
  int jw = threadIdx.x >> 6;
  int lane = threadIdx.x & 63;
  switch (jw) {
    case 0: prod_body<0>(xT, xr, g, an, out, ot[0], n, bc, lane); break;
    case 1: prod_body<1>(xT, xr, g, an, out, ot[1], n, bc, lane); break;
    case 2: prod_body<2>(xT, xr, g, an, out, ot[2], n, bc, lane); break;
    case 3: prod_body<3>(xT, xr, g, an, out, ot[3], n, bc, lane); break;
  }
}

// ---------------------------------------------------------------------------
extern "C" void kernel_launch(void* const* d_in, const int* in_sizes, int n_in,
                              void* d_out, int out_size, void* d_ws, size_t ws_size,
                              hipStream_t stream) {
  (void)n_in; (void)out_size; (void)ws_size;
  const float* x    = (const float*)d_in[0];
  const float* wgp  = (const float*)d_in[1];
  const float* wlin = (const float*)d_in[2];
  const float* blin = (const float*)d_in[3];
  const float* an   = (const float*)d_in[4];
  const int*   pidx = (const int*)d_in[7];
  int P = in_sizes[7] / 3;

  float* ws  = (float*)d_ws;
  float* xT  = ws;                // 2,097,152 floats (8 MB)
  float* xrT = ws + 2097152;      // 2,097,152 floats (8 MB)
  float* Wt  = ws + 4194304;      // 65,536 floats (256 KB)
  float* g   = ws + 4259840;      // 8,192 floats (32 KB)

  kprep<<<800, 256, 0, stream>>>(x, wlin, wgp, pidx, P, xT, Wt, g);
  klin<<<512, 256, 0, stream>>>(xT, Wt, blin, xrT);
  kprod<<<512, 256, 0, stream>>>(xT, xrT, g, an, (float*)d_out);
}